// Round 5
// baseline (185.991 us; speedup 1.0000x reference)
//
#include <hip/hip_runtime.h>

// Round 5: flash = KVBLK=32 double-buffered, ONE barrier per tile (stage at top,
// drain at bottom), setprio around MFMA clusters. MLP: W1 precombined so
// dis_x = [guess || v] (K=512). gemm_wide (BM=64) for proj/MLP.

typedef _Float16 f16;
typedef _Float16 h8_t  __attribute__((ext_vector_type(8)));
typedef _Float16 h4_t  __attribute__((ext_vector_type(4)));
typedef float    f4_t  __attribute__((ext_vector_type(4)));
typedef float    f16x  __attribute__((ext_vector_type(16)));
typedef unsigned int u4_t  __attribute__((ext_vector_type(4)));

#define LOG2E 1.4426950408889634f

__device__ __forceinline__ void llds16(const f16* g, f16* s) {
    __builtin_amdgcn_global_load_lds(
        (const __attribute__((address_space(1))) void*)g,
        (__attribute__((address_space(3))) void*)s, 16, 0, 0);
}
__device__ __forceinline__ unsigned int pk2(float a, float b) {
    auto h = __builtin_amdgcn_cvt_pkrtz(a, b);
    return __builtin_bit_cast(unsigned int, h);
}

// ---------------------- weights f32->f16 + W1 combine: [W1a+W1c | W1b-W1c]
__global__ __launch_bounds__(256)
void cvt_weights(const float* __restrict__ Wa, const float* __restrict__ Wg,
                 const float* __restrict__ W1, const float* __restrict__ W2,
                 f16* __restrict__ oa, f16* __restrict__ og,
                 f16* __restrict__ o1c, f16* __restrict__ o2)
{
    int i = blockIdx.x * 256 + threadIdx.x;   // quad index; total 73728
    if (i < 40960) {
        const float* s; f16* d; int off;
        if (i < 16384)      { s = Wa; d = oa; off = i; }
        else if (i < 32768) { s = Wg; d = og; off = i - 16384; }
        else                { s = W2; d = o2; off = i - 32768; }
        f4_t v = ((const f4_t*)s)[off];
        h4_t h;
        h[0] = (f16)v[0]; h[1] = (f16)v[1]; h[2] = (f16)v[2]; h[3] = (f16)v[3];
        ((h4_t*)d)[off] = h;
    } else {
        int off = i - 40960;                  // [0, 32768): W1comb [256][512]
        int j = off >> 7, c0 = (off & 127) * 4;
        const float* r = W1 + (size_t)j * 768;
        f4_t v0, v1;
        if (c0 < 256) { v0 = *(const f4_t*)(r + c0); v1 = *(const f4_t*)(r + 512 + c0); }
        else          { v0 = *(const f4_t*)(r + c0); v1 = *(const f4_t*)(r + 256 + c0); }
        h4_t h;
        #pragma unroll
        for (int e = 0; e < 4; e++)
            h[e] = (f16)(c0 < 256 ? v0[e] + v1[e] : v0[e] - v1[e]);
        ((h4_t*)o1c)[off] = h;
    }
}

// ------------------------------------------------- transpose anchor -> Vt f16
__global__ __launch_bounds__(256)
void transpose_f16(const float* __restrict__ src, f16* __restrict__ dst)
{
    __shared__ float tile[32][33];
    const int kb = blockIdx.x, db = blockIdx.y;
    const int t  = threadIdx.x;
    const int ty = t >> 3, tx4 = (t & 7) * 4;
    f4_t v = *(const f4_t*)(src + (size_t)(kb * 32 + ty) * 256 + db * 32 + tx4);
    tile[ty][tx4 + 0] = v[0]; tile[ty][tx4 + 1] = v[1];
    tile[ty][tx4 + 2] = v[2]; tile[ty][tx4 + 3] = v[3];
    __syncthreads();
    h4_t h;
    h[0] = (f16)tile[tx4 + 0][ty]; h[1] = (f16)tile[tx4 + 1][ty];
    h[2] = (f16)tile[tx4 + 2][ty]; h[3] = (f16)tile[tx4 + 3][ty];
    *(h4_t*)(dst + (size_t)(db * 32 + ty) * 8192 + kb * 32 + tx4) = h;
}

// --------------- C = scale*(A @ B^T + bias) [PReLU]; BM=64, BN via template
template<int ACT, int SRC32, int BN>
__global__ __launch_bounds__(256)
void gemm_wide(const void* __restrict__ A, const f16* __restrict__ B,
               const float* __restrict__ bias, const float* __restrict__ act_a,
               float scale, f16* __restrict__ C, int M, int N, int K)
{
    constexpr int BM = 64, BK = 32, LDA = 40, LDB = 40, NF = BN / 64;
    __shared__ f16 As[BM * LDA];
    __shared__ f16 Bs[BN * LDB];
    const int t = threadIdx.x;
    const int w = t >> 6, l = t & 63, lg = l >> 4, lr = l & 15;
    const int bm = blockIdx.x, bn = blockIdx.y;
    f4_t acc[4][NF] = {};

    for (int kt = 0; kt < K; kt += BK) {
        {   // A tile 64x32
            int row = t >> 2, c8 = (t & 3) * 8;
            if constexpr (SRC32) {
                const float* Af = (const float*)A + (size_t)(bm * BM + row) * K + kt + c8;
                f4_t v0 = *(const f4_t*)Af;
                f4_t v1 = *(const f4_t*)(Af + 4);
                h8_t h;
                h[0]=(f16)v0[0]; h[1]=(f16)v0[1]; h[2]=(f16)v0[2]; h[3]=(f16)v0[3];
                h[4]=(f16)v1[0]; h[5]=(f16)v1[1]; h[6]=(f16)v1[2]; h[7]=(f16)v1[3];
                *(h8_t*)(&As[row * LDA + c8]) = h;
            } else {
                *(u4_t*)(&As[row * LDA + c8]) =
                    *(const u4_t*)((const f16*)A + (size_t)(bm * BM + row) * K + kt + c8);
            }
        }
        #pragma unroll
        for (int i = 0; i < BN / 64; i++) {  // B tile BNx32
            int s = t + i * 256;
            int row = s >> 2, c8 = (s & 3) * 8;
            *(u4_t*)(&Bs[row * LDB + c8]) =
                *(const u4_t*)(B + (size_t)(bn * BN + row) * K + kt + c8);
        }
        __syncthreads();
        h8_t af[4], bf[NF];
        #pragma unroll
        for (int mf = 0; mf < 4; mf++)
            af[mf] = *(const h8_t*)(&As[(mf * 16 + lr) * LDA + lg * 8]);
        #pragma unroll
        for (int nf = 0; nf < NF; nf++)
            bf[nf] = *(const h8_t*)(&Bs[(w * (BN/4) + nf * 16 + lr) * LDB + lg * 8]);
        #pragma unroll
        for (int mf = 0; mf < 4; mf++)
            #pragma unroll
            for (int nf = 0; nf < NF; nf++)
                acc[mf][nf] = __builtin_amdgcn_mfma_f32_16x16x32_f16(
                    af[mf], bf[nf], acc[mf][nf], 0, 0, 0);
        __syncthreads();
    }

    float av = 0.f;
    if constexpr (ACT) av = *act_a;
    #pragma unroll
    for (int mf = 0; mf < 4; mf++)
        #pragma unroll
        for (int nf = 0; nf < NF; nf++)
            #pragma unroll
            for (int r = 0; r < 4; r++) {
                int row = bm * BM + mf * 16 + lg * 4 + r;
                int col = bn * BN + w * (BN/4) + nf * 16 + lr;
                float v = (acc[mf][nf][r] + bias[col]) * scale;
                if constexpr (ACT) v = v > 0.f ? v : av * v;
                C[(size_t)row * N + col] = (f16)v;
            }
}

// ------------------------------------------------------------- flash attention
// Q pre-scaled by log2(e). 512 blocks: sl=bid&7 (XCD-pinned slice), qb=bid>>3.
// 4 waves x 32 q-rows. KVBLK=32 double-buffered, ONE barrier per tile.
// K LDS [32][256]: byte = r*512 + (cb ^ ((r&15)<<4))
// V LDS [256][32]: byte = d*64  + (cb ^ (((d>>1)&3)<<4))
__global__ __launch_bounds__(256, 2)
void flash_attn(const f16* __restrict__ Q, const f16* __restrict__ Kc,
                const f16* __restrict__ Vt, f16* __restrict__ OPN,
                float* __restrict__ mpart, float* __restrict__ lpart)
{
    constexpr int D = 256, BKV = 32, NK = 8192, SL = 1024, NT = SL / BKV;  // 32
    __shared__ f16 Ks0[BKV * D], Ks1[BKV * D];   // 16 KB each
    __shared__ f16 Vs0[D * BKV], Vs1[D * BKV];   // 16 KB each
    const int t = threadIdx.x, w = t >> 6, l = t & 63;
    const int q = l & 31, hi = l >> 5;
    const int sl = blockIdx.x & 7, qb = blockIdx.x >> 3;
    const int k0b = sl * SL;
    const int qg0 = qb * 128 + w * 32;

    // Q fragments (64 VGPR)
    h8_t qf[16];
    {
        const f16* qr = Q + (size_t)(qg0 + q) * D + hi * 8;
        #pragma unroll
        for (int ks = 0; ks < 16; ks++) qf[ks] = *(const h8_t*)(qr + ks * 16);
    }

    // staging lane constants (inverse-swizzled global source, linear LDS dest)
    const int rK   = t >> 5;                         // K row = i*8 + rK
    const int keyV = 8 * ((t & 3) ^ ((t >> 3) & 3)); // V key elem
    const int dVi  = t >> 2;                         // V d = i*64 + dVi

    auto stage = [&](int k0, f16* kd, f16* vd) {
        #pragma unroll
        for (int i = 0; i < 4; i++) {
            const int r  = i * 8 + rK;
            const int ce = 8 * ((t & 31) ^ (r & 15));
            llds16(Kc + (size_t)(k0 + r) * D + ce, kd + i * 2048 + t * 8);
        }
        #pragma unroll
        for (int i = 0; i < 4; i++) {
            const int d0 = i * 64 + dVi;
            llds16(Vt + (size_t)d0 * NK + k0 + keyV, vd + i * 2048 + t * 8);
        }
    };

    stage(k0b, Ks0, Vs0);
    __syncthreads();

    f16x o[8] = {};
    float m_run = -1e30f, l_run = 0.f;
    const int kswz = (q & 15) << 4;
    const int vswz = ((q >> 1) & 3) << 4;

    auto tile = [&](int kv, const f16* kr, const f16* vr, f16* kw, f16* vw) {
        if (kv + 1 < NT) stage(k0b + (kv + 1) * BKV, kw, vw);  // full-tile window

        // ---- QK^T (swapped): C rows=key, cols=q
        f16x sa;
        #pragma unroll
        for (int r = 0; r < 16; r++) sa[r] = 0.f;
        __builtin_amdgcn_s_setprio(1);
        #pragma unroll
        for (int ks = 0; ks < 16; ks++) {
            const int cb = ((ks * 32) | (hi << 4)) ^ kswz;
            h8_t a0 = *(const h8_t*)((const char*)kr + q * 512 + cb);
            sa = __builtin_amdgcn_mfma_f32_32x32x16_f16(a0, qf[ks], sa, 0, 0, 0);
        }
        __builtin_amdgcn_s_setprio(0);

        // ---- online softmax (log2 domain), defer-max
        float m01 = fmaxf(sa[0], sa[1]),  m23 = fmaxf(sa[2], sa[3]);
        float m45 = fmaxf(sa[4], sa[5]),  m67 = fmaxf(sa[6], sa[7]);
        float m89 = fmaxf(sa[8], sa[9]),  mab = fmaxf(sa[10], sa[11]);
        float mcd = fmaxf(sa[12], sa[13]), mef = fmaxf(sa[14], sa[15]);
        float mt = fmaxf(fmaxf(fmaxf(m01, m23), fmaxf(m45, m67)),
                         fmaxf(fmaxf(m89, mab), fmaxf(mcd, mef)));
        mt = fmaxf(mt, __shfl_xor(mt, 32));
        if (!__all(mt <= m_run + 8.0f)) {
            const float mnew = fmaxf(m_run, mt);
            const float corr = exp2f(m_run - mnew);
            #pragma unroll
            for (int r = 0; r < 16; r++) {
                const float c = __shfl(corr, (r & 3) + 8 * (r >> 2) + 4 * hi);
                #pragma unroll
                for (int nb = 0; nb < 8; nb++) o[nb][r] *= c;
            }
            l_run *= corr;
            m_run = mnew;
        }
        float rs = 0.f;
        #pragma unroll
        for (int r = 0; r < 16; r++) { sa[r] = exp2f(sa[r] - m_run); rs += sa[r]; }
        rs += __shfl_xor(rs, 32);
        l_run += rs;

        // ---- PV: A = packed P, B = V from swizzled LDS
        __builtin_amdgcn_s_setprio(1);
        #pragma unroll
        for (int s = 0; s < 2; s++) {
            unsigned int w00 = pk2(sa[8*s+0], sa[8*s+1]);
            unsigned int w01 = pk2(sa[8*s+2], sa[8*s+3]);
            unsigned int w10 = pk2(sa[8*s+4], sa[8*s+5]);
            unsigned int w11 = pk2(sa[8*s+6], sa[8*s+7]);
            asm volatile("v_permlane32_swap_b32 %0, %1" : "+v"(w00), "+v"(w10));
            asm volatile("v_permlane32_swap_b32 %0, %1" : "+v"(w01), "+v"(w11));
            u4_t up; up[0] = w00; up[1] = w01; up[2] = w10; up[3] = w11;
            const h8_t apv = __builtin_bit_cast(h8_t, up);
            const int cb = ((s * 32) | (hi << 4)) ^ vswz;
            #pragma unroll
            for (int nb = 0; nb < 8; nb++) {
                h8_t bf = *(const h8_t*)((const char*)vr + nb * 2048 + q * 64 + cb);
                o[nb] = __builtin_amdgcn_mfma_f32_32x32x16_f16(apv, bf, o[nb], 0, 0, 0);
            }
        }
        __builtin_amdgcn_s_setprio(0);

        __syncthreads();   // drain next-tile stage (full-tile window) + publish
    };

    for (int kv = 0; kv < NT; kv += 2) {
        tile(kv,     Ks0, Vs0, Ks1, Vs1);
        tile(kv + 1, Ks1, Vs1, Ks0, Vs0);
    }

    // ---- normalized f16 partial O + (m, l) per slice
    #pragma unroll
    for (int r = 0; r < 16; r++) {
        const int qr = (r & 3) + 8 * (r >> 2) + 4 * hi;
        const float linv = 1.0f / __shfl(l_run, qr);
        const size_t rowoff = ((size_t)sl * NK + qg0 + qr) * D;
        #pragma unroll
        for (int nb = 0; nb < 8; nb++)
            OPN[rowoff + nb * 32 + q] = (f16)(o[nb][r] * linv);
    }
    if (hi == 0) {
        mpart[(size_t)sl * NK + qg0 + q] = m_run;
        lpart[(size_t)sl * NK + qg0 + q] = l_run;
    }
}

// --------------------- combine 8 slice partials, write dis2 = [guess || v] f16
__global__ __launch_bounds__(256)
void build_qv(const float* __restrict__ guess, const f16* __restrict__ OPN,
              const float* __restrict__ mp, const float* __restrict__ lp,
              f16* __restrict__ dis2)
{
    const int m = blockIdx.x, d = threadIdx.x;
    float M = -3.0e38f;
    #pragma unroll
    for (int s = 0; s < 8; s++) M = fmaxf(M, mp[s * 8192 + m]);
    float wsum = 0.f, num = 0.f;
    #pragma unroll
    for (int s = 0; s < 8; s++) {
        float c = exp2f(mp[s * 8192 + m] - M) * lp[s * 8192 + m];
        wsum += c;
        num  += c * (float)OPN[((size_t)s * 8192 + m) * 256 + d];
    }
    const float v = num / wsum;
    dis2[(size_t)m * 512 + d]       = (f16)guess[(size_t)m * 256 + d];
    dis2[(size_t)m * 512 + 256 + d] = (f16)v;
}

// ------------------------------------------------------ out = h2 @ W3^T + b3
__global__ __launch_bounds__(256)
void final_dot(const f16* __restrict__ h2, const float* __restrict__ W3,
               const float* __restrict__ b3, float* __restrict__ out)
{
    const int t = threadIdx.x, w = t >> 6, l = t & 63;
    const int row = blockIdx.x * 4 + w;
    const f16* hr = h2 + (size_t)row * 128;
    float s = (float)hr[l] * W3[l] + (float)hr[64 + l] * W3[64 + l];
    #pragma unroll
    for (int m = 1; m < 64; m <<= 1) s += __shfl_xor(s, m);
    if (l == 0) out[row] = s + b3[0];
}

// ============================================================================
extern "C" void kernel_launch(void* const* d_in, const int* in_sizes, int n_in,
                              void* d_out, int out_size, void* d_ws, size_t ws_size,
                              hipStream_t stream)
{
    const float* anchor = (const float*)d_in[0];
    const float* guess  = (const float*)d_in[1];
    const float* Wa = (const float*)d_in[2];
    const float* ba = (const float*)d_in[3];
    const float* Wg = (const float*)d_in[4];
    const float* bg = (const float*)d_in[5];
    const float* W1 = (const float*)d_in[6];
    const float* b1 = (const float*)d_in[7];
    const float* a1 = (const float*)d_in[8];
    const float* W2 = (const float*)d_in[9];
    const float* b2 = (const float*)d_in[10];
    const float* a2 = (const float*)d_in[11];
    const float* W3 = (const float*)d_in[12];
    const float* b3 = (const float*)d_in[13];
    float* out = (float*)d_out;
    char* ws = (char*)d_ws;

    const size_t MB = 1u << 20;
    f16* GE16 = (f16*)(ws + 0 * MB);                    // Q (x log2e)   4 MB
    f16* AC16 = (f16*)(ws + 4 * MB);                    // K             4 MB
    f16* VT16 = (f16*)(ws + 8 * MB);                    // V^T           4 MB
    f16* OPN  = (f16*)(ws + 12 * MB);                   // 8x[8192][256] 32 MB
    f16* WA16 = (f16*)(ws + 44 * MB);                   // 128 KB
    f16* WG16 = (f16*)(ws + 44 * MB + 128 * 1024);      // 128 KB
    f16* W1C  = (f16*)(ws + 44 * MB + 256 * 1024);      // 256 KB [256][512]
    f16* W216 = (f16*)(ws + 44 * MB + 512 * 1024);      // 64 KB
    float* MP = (float*)(ws + 45 * MB);                 // 256 KB
    float* LP = (float*)(ws + 45 * MB + 256 * 1024);    // 256 KB
    f16* H2   = (f16*)(ws + 46 * MB);                   // 2 MB
    // aliases after flash:
    f16* DIS2 = (f16*)(ws + 0 * MB);                    // [8192][512] 8 MB (over Q/K)
    f16* H1   = (f16*)(ws + 8 * MB);                    // 4 MB (over VT16)

    cvt_weights<<<288, 256, 0, stream>>>(Wa, Wg, W1, W2, WA16, WG16, W1C, W216);
    transpose_f16<<<dim3(256, 8), 256, 0, stream>>>(anchor, VT16);

    gemm_wide<0, 1, 128><<<dim3(128, 2), 256, 0, stream>>>(
        guess, WG16, bg, nullptr, LOG2E, GE16, 8192, 256, 256);
    gemm_wide<0, 1, 128><<<dim3(128, 2), 256, 0, stream>>>(
        anchor, WA16, ba, nullptr, 1.0f, AC16, 8192, 256, 256);

    flash_attn<<<512, 256, 0, stream>>>(GE16, AC16, VT16, OPN, MP, LP);

    build_qv<<<8192, 256, 0, stream>>>(guess, OPN, MP, LP, DIS2);

    gemm_wide<1, 0, 128><<<dim3(128, 2), 256, 0, stream>>>(
        DIS2, W1C, b1, a1, 1.0f, H1, 8192, 256, 512);
    gemm_wide<1, 0, 128><<<dim3(128, 1), 256, 0, stream>>>(
        H1, W216, b2, a2, 1.0f, H2, 8192, 128, 256);
    final_dot<<<2048, 256, 0, stream>>>(H2, W3, b3, out);
}